// Round 3
// baseline (346.524 us; speedup 1.0000x reference)
//
#include <hip/hip_runtime.h>

namespace {
constexpr int Hn = 512, Wn = 512, Cn = 32, Gn = 16;
constexpr int WHn = 227, WWn = 227;
constexpr int OHn = Hn - WHn;        // 285
constexpr int OWn = Wn - WWn;        // 285
constexpr int PTn = (Hn - OHn) / 2;  // 113
constexpr int PLn = (Wn - OWn) / 2;  // 113
constexpr float EPSn = 1e-5f;
constexpr int CHUNKS = 8;            // row-chunks per (n,g) -> 1024 blocks
constexpr int RPC = 36;              // rows per chunk (last chunk: 33)
}

// One block per (n, g, chunk-of-rows). 512 threads = one per column.
// f32 vertical 227-row sliding window (error ~1e-6 on output, 7x slack vs
// threshold); 4 output rows per scan-section (3 barriers / 4 rows);
// next-iteration slide rows prefetched before the scan.
// XCD swizzle: all 8 chunks of one ng land on one XCD (2 MB/group fits 4 MB
// L2; ramps overlap 190/227 rows -> re-reads become L2 hits).
// Window for stat (h,w): input rows h+1..h+227, cols w+1..w+227.
__global__ __launch_bounds__(512, 8) void lcn_stats(const float* __restrict__ x,
                                                    float2* __restrict__ stats) {
  const int b = blockIdx.x;
  const int X = b & 7;               // intended XCD (round-robin heuristic)
  const int s = b >> 3;
  const int ng = X + 8 * (s >> 3);   // n*16 + g ; all chunks of ng share XCD
  const int chunk = s & 7;
  const int n = ng >> 4;
  const int g = ng & 15;
  const int w = threadIdx.x;
  const int lane = w & 63;
  const int wid = w >> 6;

  const float* __restrict__ x0 = x + (size_t)(n * Cn + g * 2) * Hn * Wn;
  const float* __restrict__ x1 = x0 + (size_t)Hn * Wn;

  const int h0 = chunk * RPC;
  const int h1 = min(OHn, h0 + RPC);

  // ---- ramp: rows h0+1 .. h0+227, 8-row unroll = 16 loads in flight ----
  float sAcc[4] = {0.f, 0.f, 0.f, 0.f};
  float qAcc[4] = {0.f, 0.f, 0.f, 0.f};
  int r = h0 + 1;
  for (; r + 7 <= h0 + WHn; r += 8) {
    float a0[8], a1[8];
    #pragma unroll
    for (int j = 0; j < 8; ++j) {
      a0[j] = x0[(size_t)(r + j) * Wn + w];
      a1[j] = x1[(size_t)(r + j) * Wn + w];
    }
    #pragma unroll
    for (int j = 0; j < 8; ++j) {
      sAcc[j & 3] += a0[j] + a1[j];
      qAcc[j & 3] += a0[j] * a0[j] + a1[j] * a1[j];
    }
  }
  for (; r <= h0 + WHn; ++r) {
    float a = x0[(size_t)r * Wn + w];
    float c = x1[(size_t)r * Wn + w];
    sAcc[0] += a + c;
    qAcc[0] += a * a + c * c;
  }
  float accS = (sAcc[0] + sAcc[1]) + (sAcc[2] + sAcc[3]);
  float accQ = (qAcc[0] + qAcc[1]) + (qAcc[2] + qAcc[3]);

  __shared__ float2 Ps[4][Wn + 1];   // Ps[r][j+1] = inclusive prefix cols 0..j
  __shared__ float2 wsum[8][4];
  const float inv_n = 1.0f / (float)(WHn * WWn * 2);

  // prefetch registers: add rows h+228+j, sub rows h+1+j (j=0..3), 2 channels
  float pa0[4], pa1[4], ps0[4], ps1[4];
  auto prefetch = [&](int hb) {
    #pragma unroll
    for (int j = 0; j < 4; ++j) {
      int ra = min(hb + WHn + 1 + j, Hn - 1);   // clamp: OOB rows are unused
      int rs = hb + 1 + j;
      pa0[j] = x0[(size_t)ra * Wn + w];
      pa1[j] = x1[(size_t)ra * Wn + w];
      ps0[j] = x0[(size_t)rs * Wn + w];
      ps1[j] = x1[(size_t)rs * Wn + w];
    }
  };
  prefetch(h0);

  for (int h = h0; h < h1; h += 4) {
    // ---- consume prefetched rows: v[r] = window(h+r), acc -> window(h+4)
    float2 v[4];
    v[0] = make_float2(accS, accQ);
    float s2 = accS, q2 = accQ;
    #pragma unroll
    for (int j = 0; j < 3; ++j) {
      s2 += (pa0[j] + pa1[j]) - (ps0[j] + ps1[j]);
      q2 += (pa0[j] * pa0[j] + pa1[j] * pa1[j])
          - (ps0[j] * ps0[j] + ps1[j] * ps1[j]);
      v[j + 1] = make_float2(s2, q2);
    }
    s2 += (pa0[3] + pa1[3]) - (ps0[3] + ps1[3]);
    q2 += (pa0[3] * pa0[3] + pa1[3] * pa1[3])
        - (ps0[3] * ps0[3] + ps1[3] * ps1[3]);
    accS = s2; accQ = q2;

    // ---- issue next iteration's loads; latency hides under the scan ----
    if (h + 4 < h1) prefetch(h + 4);

    // ---- 4 independent 512-wide inclusive scans (shared barriers) ----
    #pragma unroll
    for (int d = 1; d < 64; d <<= 1) {
      #pragma unroll
      for (int rr = 0; rr < 4; ++rr) {
        float sx = __shfl_up(v[rr].x, d, 64);
        float sy = __shfl_up(v[rr].y, d, 64);
        if (lane >= d) { v[rr].x += sx; v[rr].y += sy; }
      }
    }
    if (lane == 63) {
      #pragma unroll
      for (int rr = 0; rr < 4; ++rr) wsum[wid][rr] = v[rr];
    }
    __syncthreads();
    float2 off[4] = {{0.f,0.f},{0.f,0.f},{0.f,0.f},{0.f,0.f}};
    #pragma unroll
    for (int i = 0; i < 7; ++i) {
      if (i < wid) {
        #pragma unroll
        for (int rr = 0; rr < 4; ++rr) {
          off[rr].x += wsum[i][rr].x; off[rr].y += wsum[i][rr].y;
        }
      }
    }
    #pragma unroll
    for (int rr = 0; rr < 4; ++rr)
      Ps[rr][w + 1] = make_float2(v[rr].x + off[rr].x, v[rr].y + off[rr].y);
    __syncthreads();

    if (w < OWn) {
      #pragma unroll
      for (int rr = 0; rr < 4; ++rr) {
        if (h + rr < h1) {
          float2 hi = Ps[rr][w + WWn + 1];
          float2 lo = Ps[rr][w + 1];
          float S = hi.x - lo.x;
          float Q = hi.y - lo.y;
          float mean = S * inv_n;
          float var = (Q - S * S * inv_n) * inv_n;
          float istd = rsqrtf(var + EPSn);
          stats[((size_t)ng * OHn + (h + rr)) * OWn + w] = make_float2(mean, istd);
        }
      }
    }
    __syncthreads();   // protect Ps/wsum before next iteration rewrites
  }
}

// out = (x - mean) * invstd * weight[c] + bias[c], float4-vectorized.
__global__ __launch_bounds__(256) void lcn_norm(const float* __restrict__ x,
                                                const float* __restrict__ weight,
                                                const float* __restrict__ bias,
                                                const float2* __restrict__ stats,
                                                float* __restrict__ out) {
  const size_t idx = (size_t)blockIdx.x * blockDim.x + threadIdx.x; // float4 id
  const int w4 = (int)(idx & (Wn / 4 - 1));       // 0..127
  const size_t row = idx >> 7;                    // (n*32+c)*512 + hh
  const int hh = (int)(row & (Hn - 1));
  const int c = (int)((row >> 9) & (Cn - 1));
  const int n = (int)(row >> 14);
  const int g = c >> 1;

  const int hp = min(max(hh - PTn, 0), OHn - 1);
  const float2* __restrict__ srow =
      stats + ((size_t)(n * Gn + g) * OHn + hp) * OWn;
  const float wt = weight[c];
  const float bs = bias[c];

  const float4 xv = reinterpret_cast<const float4*>(x)[idx];
  float4 ov;
  const int wwb = w4 * 4;
  {
    int wp = min(max(wwb + 0 - PLn, 0), OWn - 1);
    float2 mv = srow[wp];
    ov.x = (xv.x - mv.x) * mv.y * wt + bs;
  }
  {
    int wp = min(max(wwb + 1 - PLn, 0), OWn - 1);
    float2 mv = srow[wp];
    ov.y = (xv.y - mv.x) * mv.y * wt + bs;
  }
  {
    int wp = min(max(wwb + 2 - PLn, 0), OWn - 1);
    float2 mv = srow[wp];
    ov.z = (xv.z - mv.x) * mv.y * wt + bs;
  }
  {
    int wp = min(max(wwb + 3 - PLn, 0), OWn - 1);
    float2 mv = srow[wp];
    ov.w = (xv.w - mv.x) * mv.y * wt + bs;
  }
  reinterpret_cast<float4*>(out)[idx] = ov;
}

extern "C" void kernel_launch(void* const* d_in, const int* in_sizes, int n_in,
                              void* d_out, int out_size, void* d_ws, size_t ws_size,
                              hipStream_t stream) {
  const float* x = (const float*)d_in[0];
  const float* weight = (const float*)d_in[1];
  const float* bias = (const float*)d_in[2];
  float* out = (float*)d_out;
  float2* stats = (float2*)d_ws;  // needs 128*285*285*8 = 83,174,400 B

  hipLaunchKernelGGL(lcn_stats, dim3(128 * CHUNKS), dim3(512), 0, stream,
                     x, stats);

  const int total4 = (8 * Cn * Hn * Wn) / 4;      // 16,777,216 float4s
  hipLaunchKernelGGL(lcn_norm, dim3(total4 / 256), dim3(256), 0, stream,
                     x, weight, bias, stats, out);
}